// Round 1
// baseline (332.842 us; speedup 1.0000x reference)
//
#include <hip/hip_runtime.h>
#include <math.h>

#define H        2880
#define H4       720      // H / 4
#define NTOK     16384
#define NEXP     128
#define KT       32       // K chunk
#define NCHUNK   90       // 2880 / 32
#define BM       128      // tokens per block
#define BN       64       // experts per block
#define XPAD     (BM + 4) // 132: 16B-aligned row, breaks write conflicts
#define WPAD     (BN + 4) // 68

// ---------------- Kernel 1: router GEMM (fp32 FMA, fp64 chunk accumulation) ----------------
__global__ __launch_bounds__(256) void router_gemm(
    const float* __restrict__ x,      // [NTOK][H]
    const float* __restrict__ w,      // [NEXP][H]
    const float* __restrict__ bias,   // [NEXP]
    float* __restrict__ logits)       // [NTOK][NEXP]
{
    __shared__ float xs[KT][XPAD];    // k-major x tile
    __shared__ float ws_[KT][WPAD];   // k-major w tile

    const int tid = threadIdx.x;
    const int bn  = blockIdx.x;       // 0..1  (expert tile) — fastest dim for L2 x-reuse
    const int bm  = blockIdx.y;       // 0..127 (token tile)
    const int t0  = bm * BM;
    const int e0  = bn * BN;
    const int tn  = tid & 15;         // expert group: 4 experts
    const int tm  = tid >> 4;         // token group: 8 tokens

    const float4* xg = reinterpret_cast<const float4*>(x);
    const float4* wg = reinterpret_cast<const float4*>(w);

    const int tokA = tid >> 3;        // 0..31
    const int kq   = tid & 7;         // float4 slot within chunk

    double acc[8][4];
    float  c32[8][4];
#pragma unroll
    for (int i = 0; i < 8; ++i)
#pragma unroll
        for (int j = 0; j < 4; ++j) { acc[i][j] = 0.0; c32[i][j] = 0.0f; }

    float4 xr0, xr1, xr2, xr3, wr0, wr1;

#define LOAD_CHUNK(c)                                                          \
    {                                                                          \
        const int ko = (c) * 8 + kq;                                           \
        xr0 = xg[(size_t)(t0 + tokA      ) * H4 + ko];                         \
        xr1 = xg[(size_t)(t0 + tokA + 32 ) * H4 + ko];                         \
        xr2 = xg[(size_t)(t0 + tokA + 64 ) * H4 + ko];                         \
        xr3 = xg[(size_t)(t0 + tokA + 96 ) * H4 + ko];                         \
        wr0 = wg[(size_t)(e0 + tokA      ) * H4 + ko];                         \
        wr1 = wg[(size_t)(e0 + tokA + 32 ) * H4 + ko];                         \
    }

#define STORE_LDS()                                                            \
    {                                                                          \
        const int kb = kq * 4;                                                 \
        xs[kb + 0][tokA      ] = xr0.x; xs[kb + 1][tokA      ] = xr0.y;        \
        xs[kb + 2][tokA      ] = xr0.z; xs[kb + 3][tokA      ] = xr0.w;        \
        xs[kb + 0][tokA + 32 ] = xr1.x; xs[kb + 1][tokA + 32 ] = xr1.y;        \
        xs[kb + 2][tokA + 32 ] = xr1.z; xs[kb + 3][tokA + 32 ] = xr1.w;        \
        xs[kb + 0][tokA + 64 ] = xr2.x; xs[kb + 1][tokA + 64 ] = xr2.y;        \
        xs[kb + 2][tokA + 64 ] = xr2.z; xs[kb + 3][tokA + 64 ] = xr2.w;        \
        xs[kb + 0][tokA + 96 ] = xr3.x; xs[kb + 1][tokA + 96 ] = xr3.y;        \
        xs[kb + 2][tokA + 96 ] = xr3.z; xs[kb + 3][tokA + 96 ] = xr3.w;        \
        ws_[kb + 0][tokA     ] = wr0.x; ws_[kb + 1][tokA     ] = wr0.y;        \
        ws_[kb + 2][tokA     ] = wr0.z; ws_[kb + 3][tokA     ] = wr0.w;        \
        ws_[kb + 0][tokA + 32] = wr1.x; ws_[kb + 1][tokA + 32] = wr1.y;        \
        ws_[kb + 2][tokA + 32] = wr1.z; ws_[kb + 3][tokA + 32] = wr1.w;        \
    }

    LOAD_CHUNK(0);
    STORE_LDS();
    __syncthreads();

    for (int c = 0; c < NCHUNK; ++c) {
        if (c < NCHUNK - 1) LOAD_CHUNK(c + 1);   // issue next-chunk global loads early

#pragma unroll 4
        for (int kk = 0; kk < KT; ++kk) {
            const float4 a0 = *reinterpret_cast<const float4*>(&xs[kk][tm * 8]);
            const float4 a1 = *reinterpret_cast<const float4*>(&xs[kk][tm * 8 + 4]);
            const float4 b  = *reinterpret_cast<const float4*>(&ws_[kk][tn * 4]);
            const float av[8] = {a0.x, a0.y, a0.z, a0.w, a1.x, a1.y, a1.z, a1.w};
            const float bv[4] = {b.x, b.y, b.z, b.w};
#pragma unroll
            for (int i = 0; i < 8; ++i)
#pragma unroll
                for (int j = 0; j < 4; ++j)
                    c32[i][j] = fmaf(av[i], bv[j], c32[i][j]);
        }

        // cascade chunk sum into fp64 accumulator (error ~1e-7 abs, near-exact)
#pragma unroll
        for (int i = 0; i < 8; ++i)
#pragma unroll
            for (int j = 0; j < 4; ++j) {
                acc[i][j] += (double)c32[i][j];
                c32[i][j] = 0.0f;
            }

        __syncthreads();
        if (c < NCHUNK - 1) STORE_LDS();
        __syncthreads();
    }

    // epilogue: + bias, write logits
    const int eb = e0 + tn * 4;
    const double b0 = (double)bias[eb + 0];
    const double b1 = (double)bias[eb + 1];
    const double b2 = (double)bias[eb + 2];
    const double b3 = (double)bias[eb + 3];
#pragma unroll
    for (int i = 0; i < 8; ++i) {
        float4 o;
        o.x = (float)(acc[i][0] + b0);
        o.y = (float)(acc[i][1] + b1);
        o.z = (float)(acc[i][2] + b2);
        o.w = (float)(acc[i][3] + b3);
        *reinterpret_cast<float4*>(&logits[(size_t)(t0 + tm * 8 + i) * NEXP + eb]) = o;
    }
}

// ---------------- Kernel 2: top-4 + softmax (one thread per token) ----------------
__global__ __launch_bounds__(256) void topk_softmax(
    const float* __restrict__ logits,   // [NTOK][NEXP]
    float* __restrict__ vals,           // [NTOK][4]
    float* __restrict__ inds)           // [NTOK][4] (float-valued indices)
{
    const int t = blockIdx.x * 256 + threadIdx.x;
    const float4* row = reinterpret_cast<const float4*>(logits + (size_t)t * NEXP);

    float v0 = -3.4e38f, v1 = -3.4e38f, v2 = -3.4e38f, v3 = -3.4e38f;
    int   i0 = 0, i1 = 0, i2 = 0, i3 = 0;

    for (int g = 0; g < NEXP / 4; ++g) {
        const float4 q = row[g];
        const float qq[4] = {q.x, q.y, q.z, q.w};
#pragma unroll
        for (int j = 0; j < 4; ++j) {
            const float v = qq[j];
            const int   e = g * 4 + j;
            // strict > keeps earliest index on ties == lax.top_k stable order
            if (v > v0)      { v3=v2; i3=i2; v2=v1; i2=i1; v1=v0; i1=i0; v0=v; i0=e; }
            else if (v > v1) { v3=v2; i3=i2; v2=v1; i2=i1; v1=v; i1=e; }
            else if (v > v2) { v3=v2; i3=i2; v2=v; i2=e; }
            else if (v > v3) { v3=v; i3=e; }
        }
    }

    const float e1 = expf(v1 - v0);
    const float e2 = expf(v2 - v0);
    const float e3 = expf(v3 - v0);
    const float s  = 1.0f + e1 + e2 + e3;

    float4 ov = {1.0f / s, e1 / s, e2 / s, e3 / s};
    float4 oi = {(float)i0, (float)i1, (float)i2, (float)i3};
    *reinterpret_cast<float4*>(&vals[(size_t)t * 4]) = ov;
    *reinterpret_cast<float4*>(&inds[(size_t)t * 4]) = oi;
}

extern "C" void kernel_launch(void* const* d_in, const int* in_sizes, int n_in,
                              void* d_out, int out_size, void* d_ws, size_t ws_size,
                              hipStream_t stream) {
    const float* x    = (const float*)d_in[0];   // [16384,2880]
    const float* w    = (const float*)d_in[1];   // [128,2880]
    const float* bias = (const float*)d_in[2];   // [128]

    float* out    = (float*)d_out;
    float* vals   = out;                          // 16384*4
    float* inds   = out + NTOK * 4;               // 16384*4
    float* logits = out + NTOK * 8;               // 16384*128

    dim3 grid1(NEXP / BN, NTOK / BM);             // (2, 128) — bn fastest for x L2 reuse
    router_gemm<<<grid1, 256, 0, stream>>>(x, w, bias, logits);

    topk_softmax<<<NTOK / 256, 256, 0, stream>>>(logits, vals, inds);
}

// Round 2
// 226.290 us; speedup vs baseline: 1.4709x; 1.4709x over previous
//
#include <hip/hip_runtime.h>
#include <math.h>

#define H        2880
#define H4       720      // H / 4
#define NTOK     16384
#define NEXP     128
#define KT       32       // K chunk
#define NCHUNK   90       // 2880 / 32
#define BM       128      // tokens per block
#define BN       64       // experts per block
#define XPAD     (BM + 4) // 132: keeps float4 reads 16B-aligned
#define WPAD     (BN + 4) // 68

// ---------------- Kernel 1: router GEMM, split-K (fp32 FMA, fp64 chunk accumulation) --------
// Writes RAW partial sums (no bias). Slice z=0 -> p0 (logits region), z>=1 -> pws[(z-1)*NTOK*NEXP].
__global__ __launch_bounds__(256) void router_gemm(
    const float* __restrict__ x,      // [NTOK][H]
    const float* __restrict__ w,      // [NEXP][H]
    float* __restrict__ p0,           // [NTOK][NEXP] partial slice 0
    float* __restrict__ pws)          // [KS-1][NTOK][NEXP] partial slices 1..
{
    __shared__ float xs[KT][XPAD];    // k-major x tile
    __shared__ float ws_[KT][WPAD];   // k-major w tile

    const int tid = threadIdx.x;
    const int bn  = blockIdx.x;       // 0..1  (expert tile)
    const int bm  = blockIdx.y;       // 0..127 (token tile)
    const int z   = blockIdx.z;       // k-slice
    const int ks  = gridDim.z;
    const int t0  = bm * BM;
    const int e0  = bn * BN;
    const int tn  = tid & 15;         // expert group: 4 experts
    const int tm  = tid >> 4;         // token group: 8 tokens

    // chunk range for this slice
    const int base = NCHUNK / ks;
    const int rem  = NCHUNK % ks;
    const int c0   = z * base + (z < rem ? z : rem);
    const int c1   = c0 + base + (z < rem ? 1 : 0);

    float* outp = (z == 0) ? p0 : (pws + (size_t)(z - 1) * NTOK * NEXP);

    const float4* xg = reinterpret_cast<const float4*>(x);
    const float4* wg = reinterpret_cast<const float4*>(w);

    const int tokA = tid >> 3;        // 0..31
    const int kq   = tid & 7;         // float4 slot within chunk

    double acc[8][4];
    float  c32[8][4];
#pragma unroll
    for (int i = 0; i < 8; ++i)
#pragma unroll
        for (int j = 0; j < 4; ++j) { acc[i][j] = 0.0; c32[i][j] = 0.0f; }

    float4 xr0, xr1, xr2, xr3, wr0, wr1;

#define LOAD_CHUNK(c)                                                          \
    {                                                                          \
        const int ko = (c) * 8 + kq;                                           \
        xr0 = xg[(size_t)(t0 + tokA      ) * H4 + ko];                         \
        xr1 = xg[(size_t)(t0 + tokA + 32 ) * H4 + ko];                         \
        xr2 = xg[(size_t)(t0 + tokA + 64 ) * H4 + ko];                         \
        xr3 = xg[(size_t)(t0 + tokA + 96 ) * H4 + ko];                         \
        wr0 = wg[(size_t)(e0 + tokA      ) * H4 + ko];                         \
        wr1 = wg[(size_t)(e0 + tokA + 32 ) * H4 + ko];                         \
    }

#define STORE_LDS()                                                            \
    {                                                                          \
        const int kb = kq * 4;                                                 \
        xs[kb + 0][tokA      ] = xr0.x; xs[kb + 1][tokA      ] = xr0.y;        \
        xs[kb + 2][tokA      ] = xr0.z; xs[kb + 3][tokA      ] = xr0.w;        \
        xs[kb + 0][tokA + 32 ] = xr1.x; xs[kb + 1][tokA + 32 ] = xr1.y;        \
        xs[kb + 2][tokA + 32 ] = xr1.z; xs[kb + 3][tokA + 32 ] = xr1.w;        \
        xs[kb + 0][tokA + 64 ] = xr2.x; xs[kb + 1][tokA + 64 ] = xr2.y;        \
        xs[kb + 2][tokA + 64 ] = xr2.z; xs[kb + 3][tokA + 64 ] = xr2.w;        \
        xs[kb + 0][tokA + 96 ] = xr3.x; xs[kb + 1][tokA + 96 ] = xr3.y;        \
        xs[kb + 2][tokA + 96 ] = xr3.z; xs[kb + 3][tokA + 96 ] = xr3.w;        \
        ws_[kb + 0][tokA     ] = wr0.x; ws_[kb + 1][tokA     ] = wr0.y;        \
        ws_[kb + 2][tokA     ] = wr0.z; ws_[kb + 3][tokA     ] = wr0.w;        \
        ws_[kb + 0][tokA + 32] = wr1.x; ws_[kb + 1][tokA + 32] = wr1.y;        \
        ws_[kb + 2][tokA + 32] = wr1.z; ws_[kb + 3][tokA + 32] = wr1.w;        \
    }

    LOAD_CHUNK(c0);
    STORE_LDS();
    __syncthreads();

    for (int c = c0; c < c1; ++c) {
        if (c + 1 < c1) LOAD_CHUNK(c + 1);   // issue next-chunk global loads early

#pragma unroll 4
        for (int kk = 0; kk < KT; ++kk) {
            const float4 a0 = *reinterpret_cast<const float4*>(&xs[kk][tm * 8]);
            const float4 a1 = *reinterpret_cast<const float4*>(&xs[kk][tm * 8 + 4]);
            const float4 b  = *reinterpret_cast<const float4*>(&ws_[kk][tn * 4]);
            const float av[8] = {a0.x, a0.y, a0.z, a0.w, a1.x, a1.y, a1.z, a1.w};
            const float bv[4] = {b.x, b.y, b.z, b.w};
#pragma unroll
            for (int i = 0; i < 8; ++i)
#pragma unroll
                for (int j = 0; j < 4; ++j)
                    c32[i][j] = fmaf(av[i], bv[j], c32[i][j]);
        }

        // cascade chunk sum into fp64 accumulator (near-exact)
#pragma unroll
        for (int i = 0; i < 8; ++i)
#pragma unroll
            for (int j = 0; j < 4; ++j) {
                acc[i][j] += (double)c32[i][j];
                c32[i][j] = 0.0f;
            }

        __syncthreads();
        if (c + 1 < c1) STORE_LDS();
        __syncthreads();
    }

    const int eb = e0 + tn * 4;
#pragma unroll
    for (int i = 0; i < 8; ++i) {
        float4 o;
        o.x = (float)acc[i][0];
        o.y = (float)acc[i][1];
        o.z = (float)acc[i][2];
        o.w = (float)acc[i][3];
        *reinterpret_cast<float4*>(&outp[(size_t)(t0 + tm * 8 + i) * NEXP + eb]) = o;
    }
}

// ---------------- Kernel 2: fused reduce(+bias) + logits write + top-4 + softmax ------------
// 4 threads per token; each scans 32 experts; 2-stage shfl_xor merge of sorted top-4 lists.
#define INSERT(v, e)                                                           \
    if ((v) > v0)      { v3=v2;i3=i2; v2=v1;i2=i1; v1=v0;i1=i0; v0=(v);i0=(e);}\
    else if ((v) > v1) { v3=v2;i3=i2; v2=v1;i2=i1; v1=(v);i1=(e); }            \
    else if ((v) > v2) { v3=v2;i3=i2; v2=(v);i2=(e); }                         \
    else if ((v) > v3) { v3=(v);i3=(e); }

__global__ __launch_bounds__(256) void reduce_topk_softmax(
    float* __restrict__ p0,             // [NTOK][NEXP] partial 0, overwritten with final logits
    const float* __restrict__ pws,      // [KS-1][NTOK][NEXP]
    const float* __restrict__ bias,     // [NEXP]
    float* __restrict__ vals,           // [NTOK][4]
    float* __restrict__ inds,           // [NTOK][4] (float-valued indices)
    int ks)
{
    const int gt   = blockIdx.x * 256 + threadIdx.x;
    const int tok  = gt >> 2;
    const int part = gt & 3;            // expert range [part*32, part*32+32)

    float4*       row4 = reinterpret_cast<float4*>(p0) + (size_t)tok * 32;
    const float4* b4   = reinterpret_cast<const float4*>(bias);

    float v0 = -3.4e38f, v1 = -3.4e38f, v2 = -3.4e38f, v3 = -3.4e38f;
    int   i0 = 0, i1 = 0, i2 = 0, i3 = 0;

#pragma unroll
    for (int g = 0; g < 8; ++g) {
        const int f4i = part * 8 + g;
        float4 s = row4[f4i];
        for (int zz = 1; zz < ks; ++zz) {
            const float4 pz = reinterpret_cast<const float4*>(
                pws + (size_t)(zz - 1) * NTOK * NEXP)[(size_t)tok * 32 + f4i];
            s.x += pz.x; s.y += pz.y; s.z += pz.z; s.w += pz.w;
        }
        const float4 bb = b4[f4i];
        s.x += bb.x; s.y += bb.y; s.z += bb.z; s.w += bb.w;
        row4[f4i] = s;                  // final logits

        const float qq[4] = {s.x, s.y, s.z, s.w};
#pragma unroll
        for (int j = 0; j < 4; ++j) {
            const float v = qq[j];
            const int   e = f4i * 4 + j;
            INSERT(v, e);
        }
    }

    // merge sorted top-4 lists across the 4 threads of this token.
    // lower expert-range list is incumbent -> strict > keeps earliest index on ties.
#pragma unroll
    for (int m = 1; m <= 2; m <<= 1) {
        float u0 = __shfl_xor(v0, m), u1 = __shfl_xor(v1, m),
              u2 = __shfl_xor(v2, m), u3 = __shfl_xor(v3, m);
        int   j0 = __shfl_xor(i0, m), j1 = __shfl_xor(i1, m),
              j2 = __shfl_xor(i2, m), j3 = __shfl_xor(i3, m);
        if (part & m) {
            // I'm the upper range: other's list is incumbent, insert mine
            float t0 = v0, t1 = v1, t2 = v2, t3 = v3;
            int   s0 = i0, s1 = i1, s2 = i2, s3 = i3;
            v0 = u0; v1 = u1; v2 = u2; v3 = u3;
            i0 = j0; i1 = j1; i2 = j2; i3 = j3;
            INSERT(t0, s0); INSERT(t1, s1); INSERT(t2, s2); INSERT(t3, s3);
        } else {
            INSERT(u0, j0); INSERT(u1, j1); INSERT(u2, j2); INSERT(u3, j3);
        }
    }

    if (part == 0) {
        const float e1 = expf(v1 - v0);
        const float e2 = expf(v2 - v0);
        const float e3 = expf(v3 - v0);
        const float s  = 1.0f + e1 + e2 + e3;
        float4 ov = {1.0f / s, e1 / s, e2 / s, e3 / s};
        float4 oi = {(float)i0, (float)i1, (float)i2, (float)i3};
        *reinterpret_cast<float4*>(&vals[(size_t)tok * 4]) = ov;
        *reinterpret_cast<float4*>(&inds[(size_t)tok * 4]) = oi;
    }
}

extern "C" void kernel_launch(void* const* d_in, const int* in_sizes, int n_in,
                              void* d_out, int out_size, void* d_ws, size_t ws_size,
                              hipStream_t stream) {
    const float* x    = (const float*)d_in[0];   // [16384,2880]
    const float* w    = (const float*)d_in[1];   // [128,2880]
    const float* bias = (const float*)d_in[2];   // [128]

    float* out    = (float*)d_out;
    float* vals   = out;                          // 16384*4
    float* inds   = out + NTOK * 4;               // 16384*4
    float* logits = out + NTOK * 8;               // 16384*128

    const size_t PBYTES = (size_t)NTOK * NEXP * sizeof(float);  // 8.39 MB per slice
    int ks = 1;
    if (ws_size >= 3 * PBYTES)      ks = 4;
    else if (ws_size >= PBYTES)     ks = 2;

    dim3 grid1(NEXP / BN, NTOK / BM, ks);         // (2, 128, ks)
    router_gemm<<<grid1, 256, 0, stream>>>(x, w, logits, (float*)d_ws);

    // 4 threads per token
    reduce_topk_softmax<<<(NTOK * 4) / 256, 256, 0, stream>>>(
        logits, (const float*)d_ws, bias, vals, inds, ks);
}